// Round 11
// baseline (227.777 us; speedup 1.0000x reference)
//
#include <hip/hip_runtime.h>
#include <hip/hip_bf16.h>

typedef __bf16 bf16_t;
typedef __bf16 bf16x8 __attribute__((ext_vector_type(8)));
typedef __bf16 bf16x4 __attribute__((ext_vector_type(4)));
typedef __bf16 bf16x2 __attribute__((ext_vector_type(2)));
typedef float  f32x4  __attribute__((ext_vector_type(4)));

#define LN_EPS 1e-5f

// B=8, T=512, C=768 -> M = 4096, 4C = 3072

// ---------------- fp32 -> bf16 conversion ----------------
__global__ __launch_bounds__(256) void k_cvt4(const float* __restrict__ s0,
                                              const float* __restrict__ s1,
                                              const float* __restrict__ s2,
                                              const float* __restrict__ s3,
                                              bf16_t* __restrict__ dst, int n4) {
    const float* s = (blockIdx.y == 0) ? s0 : (blockIdx.y == 1) ? s1 : (blockIdx.y == 2) ? s2 : s3;
    bf16_t* d = dst + (size_t)blockIdx.y * ((size_t)n4 * 4);
    int i = blockIdx.x * 256 + threadIdx.x;
    if (i < n4) {
        float4 v = ((const float4*)s)[i];
        bf16x4 o;
        o.x = (bf16_t)v.x; o.y = (bf16_t)v.y; o.z = (bf16_t)v.z; o.w = (bf16_t)v.w;
        ((bf16x4*)d)[i] = o;
    }
}

__global__ __launch_bounds__(256) void k_cvt2(const float* __restrict__ s0,
                                              const float* __restrict__ s1,
                                              bf16_t* __restrict__ dst, int n4) {
    const float* s = (blockIdx.y == 0) ? s0 : s1;
    bf16_t* d = dst + (size_t)blockIdx.y * ((size_t)n4 * 4);
    int i = blockIdx.x * 256 + threadIdx.x;
    if (i < n4) {
        float4 v = ((const float4*)s)[i];
        bf16x4 o;
        o.x = (bf16_t)v.x; o.y = (bf16_t)v.y; o.z = (bf16_t)v.z; o.w = (bf16_t)v.w;
        ((bf16x4*)d)[i] = o;
    }
}

// ---------------- LayerNorm (one block per row of C=768), bf16 out ----------------
__global__ __launch_bounds__(256) void k_ln(const float* __restrict__ x,
                                            const float* __restrict__ w,
                                            const float* __restrict__ b,
                                            bf16_t* __restrict__ out, int C) {
    int row = blockIdx.x;
    const float* xr = x + (long)row * C;
    int tid = threadIdx.x;
    float s = 0.f, s2 = 0.f;
    for (int i = tid; i < C; i += 256) { float v = xr[i]; s += v; s2 += v * v; }
    for (int m = 32; m; m >>= 1) { s += __shfl_xor(s, m, 64); s2 += __shfl_xor(s2, m, 64); }
    __shared__ float red[8];
    int wv = tid >> 6;
    if ((tid & 63) == 0) { red[wv] = s; red[4 + wv] = s2; }
    __syncthreads();
    float ts  = red[0] + red[1] + red[2] + red[3];
    float ts2 = red[4] + red[5] + red[6] + red[7];
    float mu  = ts / C;
    float var = ts2 / C - mu * mu;
    float rstd = rsqrtf(var + LN_EPS);
    bf16_t* orow = out + (long)row * C;
    for (int i = tid; i < C; i += 256)
        orow[i] = (bf16_t)((xr[i] - mu) * rstd * w[i] + b[i]);
}

// ---------------- B-stationary bf16 MFMA GEMM (barrier-free K-loop) ----------------
// C[M][N](+=) A[M][Kslice] * Bw[N][Kslice]^T.
// Block: 512 thr = 8 waves (4 M-groups x 2 N-groups); covers 512 M-rows x 96 N-cols
// x Kloc=768. B panel [96][768] staged ONCE into LDS (144 KB, 1 block/CU, one
// __syncthreads total: 9216 uint4s = 18 iters x 512 thr). Then per wave, a
// BARRIER-FREE loop over 24 K-steps: A frags stream global->VGPR (double-buffered,
// issued one K-step early), B frags ds_read from resident LDS. The R2-R9 wall
// (block-wide barrier per K-step serializing on the slowest load) is removed.
// LDS swizzle: 16B slot phys = logical ^ (row&7) -> B-frag read bank-balanced;
// read key (row&7) == fr&7 because rb in {0,48} and ni*16 are both 0 mod 8.
// Per-XCD decode: 2 mchunks x 16 ci -> A+B L2 set ~3.9 MB (GEMM1/2).
// Grid MUST be 256 (8 mc x 32 ci), block 512.
// EPI 0: store bf16   EPI 1: store bf16(relu^2)   EPI 3: atomicAdd fp32
template <int EPI>
__global__ __launch_bounds__(512, 2) void k_gemm_bstat(const bf16_t* __restrict__ A,
                                                       const bf16_t* __restrict__ Bw,
                                                       void* __restrict__ Cout,
                                                       int N, int Ktot, int nks) {
    __shared__ __align__(16) bf16_t Bs[96][768];    // 147456 B
    const int tid  = threadIdx.x;
    const int lane = tid & 63, wid = tid >> 6;      // wid 0..7
    const int gm = wid >> 1, gn = wid & 1;          // 4 M-groups x 2 N-groups
    const int fr = lane & 15, ko = lane >> 4;       // frag row / k-octet

    // block decode: 256 blocks; per XCD: 2 mchunks x 16 ci  (bijective)
    int bid = blockIdx.x;
    int xcd = bid & 7, loc = bid >> 3;              // loc 0..31
    int mc  = (xcd & 3) * 2 + (loc >> 4);           // 0..7
    int ci  = (xcd >> 2) * 16 + (loc & 15);         // 0..31
    int bn  = ci / nks, ks = ci % nks;

    // ---- stage B panel [96 x 768] once, XOR-swizzled 16B slots (18 x 512 uint4) ----
    {
        const bf16_t* gb = Bw + (size_t)(bn * 96) * Ktot + (size_t)ks * 768;
#pragma unroll
        for (int i = 0; i < 18; ++i) {
            int idx = tid + i * 512;                // 0..9215
            int r = idx / 96, s = idx % 96;         // r: panel row, s: 16B slot
            uint4 v = *(const uint4*)(gb + (size_t)r * Ktot + s * 8);
            *(uint4*)&Bs[r][(s ^ (r & 7)) * 8] = v;
        }
    }

    f32x4 acc[8][3];
#pragma unroll
    for (int i = 0; i < 8; i++)
#pragma unroll
        for (int j = 0; j < 3; j++) acc[i][j] = (f32x4){0.f, 0.f, 0.f, 0.f};

    const int rbase = mc * 512 + gm * 128;          // wave's first M-row
    const bf16_t* ga = A + (size_t)(rbase + fr) * Ktot + (size_t)ks * 768 + ko * 8;
    const size_t rs16 = (size_t)16 * Ktot;
    const int rb = gn * 48;                         // wave's B-panel row base
    const int f8 = fr & 7;                          // read-swizzle key

    __syncthreads();                                // B panel resident (only barrier)

#define LOADA(dst, kt)                                                          \
    do {                                                                        \
        _Pragma("unroll")                                                       \
        for (int mi = 0; mi < 8; ++mi)                                          \
            dst[mi] = *(const bf16x8*)(ga + (size_t)mi * rs16 + (kt) * 32);     \
    } while (0)

#define READB(bf, kt)                                                           \
    do {                                                                        \
        _Pragma("unroll")                                                       \
        for (int ni = 0; ni < 3; ++ni)                                          \
            bf[ni] = *(const bf16x8*)&Bs[rb + ni * 16 + fr][(((kt) * 4 + ko) ^ f8) * 8]; \
    } while (0)

#define MFMAB(af, bf)                                                                        \
    do {                                                                                     \
        __builtin_amdgcn_s_setprio(1);                                                       \
        _Pragma("unroll")                                                                    \
        for (int mi = 0; mi < 8; ++mi)                                                       \
            _Pragma("unroll")                                                                \
            for (int ni = 0; ni < 3; ++ni)                                                   \
                acc[mi][ni] = __builtin_amdgcn_mfma_f32_16x16x32_bf16(af[mi], bf[ni], acc[mi][ni], 0, 0, 0); \
        __builtin_amdgcn_s_setprio(0);                                                       \
    } while (0)

    bf16x8 afA[8], afB[8], bfr[3];
    LOADA(afA, 0);
    for (int kt = 0; kt < 24; kt += 2) {
        LOADA(afB, kt + 1);                         // in flight during MFMA(afA)
        READB(bfr, kt);
        MFMAB(afA, bfr);
        if (kt + 2 < 24) LOADA(afA, kt + 2);        // in flight during MFMA(afB)
        READB(bfr, kt + 1);
        MFMAB(afB, bfr);
    }

#undef LOADA
#undef READB
#undef MFMAB

    const int col0 = bn * 96 + rb;
#pragma unroll
    for (int mi = 0; mi < 8; mi++) {
#pragma unroll
        for (int ni = 0; ni < 3; ni++) {
            int row = rbase + mi * 16 + ko * 4;     // C/D: col=lane&15, row=(lane>>4)*4+r
            int col = col0 + ni * 16 + fr;
#pragma unroll
            for (int r = 0; r < 4; r++) {
                float val = acc[mi][ni][r];
                size_t off = (size_t)(row + r) * N + col;
                if (EPI == 0) {
                    ((bf16_t*)Cout)[off] = (bf16_t)val;
                } else if (EPI == 1) {
                    float t = fmaxf(val, 0.f);
                    ((bf16_t*)Cout)[off] = (bf16_t)(t * t);
                } else {
                    atomicAdd(&((float*)Cout)[off], val);
                }
            }
        }
    }
}

// ---------------- WKV chunked scan (y4 bf16), 2 channels/thread ----------------
// y4 layout per (b,t): [ r(768) | k(768) | v(768) | router(768) ]
__global__ __launch_bounds__(256) void k_scan_local(const bf16_t* __restrict__ y4,
                                                    const float* __restrict__ tmw,
                                                    float* __restrict__ wkvl,
                                                    float* __restrict__ states) {
    int idx = blockIdx.x * 256 + threadIdx.x;  // 8*16*384 = 49152
    int cp  = idx % 384;
    int rem = idx / 384;
    int ch  = rem & 15;
    int b   = rem >> 4;
    int c   = cp * 2;
    float d0 = expf(-expf(tmw[c]));
    float d1 = expf(-expf(tmw[c + 1]));
    const bf16_t* base = y4 + ((size_t)(b * 512 + ch * 32)) * 3072 + c;
    float*        wout = wkvl + ((size_t)(b * 512 + ch * 32)) * 768 + c;
    float s0 = 0.f, s1 = 0.f;
#pragma unroll 4
    for (int i = 0; i < 32; i++) {
        bf16x2 k2 = *(const bf16x2*)(base + (size_t)i * 3072 + 768);
        bf16x2 v2 = *(const bf16x2*)(base + (size_t)i * 3072 + 1536);
        s0 = s0 * d0 + (float)k2.x * (float)v2.x;
        s1 = s1 * d1 + (float)k2.y * (float)v2.y;
        *(float2*)(wout + (size_t)i * 768) = make_float2(s0, s1);
    }
    *(float2*)(states + ((size_t)(b * 16 + ch)) * 768 + c) = make_float2(s0, s1);
}

__global__ __launch_bounds__(256) void k_scan_carry(const float* __restrict__ states,
                                                    const float* __restrict__ tmw,
                                                    float* __restrict__ carries) {
    int idx = blockIdx.x * 256 + threadIdx.x;  // b*768 + c
    int c = idx % 768, b = idx / 768;
    float dL = expf(-expf(tmw[c]) * 32.f);
    float s = 0.f;
    for (int ch = 0; ch < 16; ch++) {
        size_t o = ((size_t)(b * 16 + ch)) * 768 + c;
        carries[o] = s;
        s = s * dL + states[o];
    }
}

// ---------------- mix + LN2 fused: one block per (b,t) row ----------------
// out = x + r*((wkv_local + carry*d^(tmod+1)) * sigmoid(router));  xx2 = LN2(out) bf16
// (out is d_out; the final GEMM atomically adds the channel-mix on top)
__global__ __launch_bounds__(256) void k_mix_ln(const bf16_t* __restrict__ y4,
                                                const float* __restrict__ wkvl,
                                                const float* __restrict__ carries,
                                                const float* __restrict__ tmw,
                                                const float* __restrict__ x,
                                                const float* __restrict__ w2,
                                                const float* __restrict__ b2,
                                                float* __restrict__ out,
                                                bf16_t* __restrict__ xx2) {
    int bt = blockIdx.x;
    int t = bt & 511, b = bt >> 9;
    int tid = threadIdx.x;
    const bf16_t* yrow = y4 + (size_t)bt * 3072;
    const float*  wl   = wkvl + (size_t)bt * 768;
    const float*  cr   = carries + ((size_t)(b * 16) + (t >> 5)) * 768;
    const float*  xr   = x + (size_t)bt * 768;
    float tn = (float)((t & 31) + 1);

    float vals[3];
    float s = 0.f, s2 = 0.f;
#pragma unroll
    for (int j = 0; j < 3; j++) {
        int c = tid + j * 256;
        float rr = (float)yrow[c];
        float gg = (float)yrow[c + 2304];
        float wk = wl[c] + cr[c] * expf(-expf(tmw[c]) * tn);
        float sig = 1.f / (1.f + expf(-gg));
        float o = fmaf(rr, wk * sig, xr[c]);
        vals[j] = o; s += o; s2 += o * o;
    }
    for (int m = 32; m; m >>= 1) { s += __shfl_xor(s, m, 64); s2 += __shfl_xor(s2, m, 64); }
    __shared__ float red[8];
    int wv = tid >> 6;
    if ((tid & 63) == 0) { red[wv] = s; red[4 + wv] = s2; }
    __syncthreads();
    float ts  = red[0] + red[1] + red[2] + red[3];
    float ts2 = red[4] + red[5] + red[6] + red[7];
    float mu  = ts * (1.f / 768.f);
    float var = ts2 * (1.f / 768.f) - mu * mu;
    float rstd = rsqrtf(var + LN_EPS);
    float* orow = out + (size_t)bt * 768;
    bf16_t* xo = xx2 + (size_t)bt * 768;
#pragma unroll
    for (int j = 0; j < 3; j++) {
        int c = tid + j * 256;
        orow[c] = vals[j];
        xo[c] = (bf16_t)((vals[j] - mu) * rstd * w2[c] + b2[c]);
    }
}

// ---------------- host-side launch ----------------
extern "C" void kernel_launch(void* const* d_in, const int* in_sizes, int n_in,
                              void* d_out, int out_size, void* d_ws, size_t ws_size,
                              hipStream_t stream) {
    const float* x    = (const float*)d_in[0];
    const float* ln1w = (const float*)d_in[1];
    const float* ln1b = (const float*)d_in[2];
    const float* Wr   = (const float*)d_in[3];
    const float* Wk   = (const float*)d_in[4];
    const float* Wv   = (const float*)d_in[5];
    const float* tmw  = (const float*)d_in[6];
    const float* Wrt  = (const float*)d_in[7];
    const float* ln2w = (const float*)d_in[8];
    const float* ln2b = (const float*)d_in[9];
    const float* Wck  = (const float*)d_in[10];
    const float* Wcv  = (const float*)d_in[11];
    float* out = (float*)d_out;
    char* ws = (char*)d_ws;

    // workspace layout (bytes)
    bf16_t* xx     = (bf16_t*)(ws + 0);          // 4096*768 bf16 (xx, reused as xx2)
    bf16_t* wcat   = (bf16_t*)(ws + 6291456);    // [4][768][768] bf16 (r,k,v,router)
    bf16_t* wckb   = (bf16_t*)(ws + 11010048);   // [3072][768] bf16
    bf16_t* wcvb   = (bf16_t*)(ws + 15728640);   // [768][3072] bf16
    bf16_t* y4     = (bf16_t*)(ws + 20447232);   // [4096][3072] bf16
    bf16_t* kcm    = (bf16_t*)(ws + 20447232);   // reuses y4 after mix
    float*  wkvl   = (float*)(ws + 70778880);    // [4096][768] fp32
    float*  states = (float*)(ws + 83361792);    // [8][16][768]
    float*  carr   = (float*)(ws + 83755008);    // [8][16][768]

    // 1) weights -> bf16
    const int n768 = 768 * 768 / 4;
    const int nbig = 3072 * 768 / 4;
    k_cvt4<<<dim3(576, 4), dim3(256), 0, stream>>>(Wr, Wk, Wv, Wrt, wcat, n768);
    k_cvt2<<<dim3(2304, 2), dim3(256), 0, stream>>>(Wck, Wcv, wckb, nbig);

    // 2) LN1
    k_ln<<<dim3(4096), dim3(256), 0, stream>>>(x, ln1w, ln1b, xx, 768);

    // 3) fused r|k|v|router GEMM: y4 = xx @ wcat^T  (M=4096, N=3072, Ktot=768)
    k_gemm_bstat<0><<<dim3(256), dim3(512), 0, stream>>>(xx, wcat, (void*)y4, 3072, 768, 1);

    // 4) wkv scan + mix(+LN2): writes x1 -> d_out, xx2 -> xx
    k_scan_local<<<dim3(192), dim3(256), 0, stream>>>(y4, tmw, wkvl, states);
    k_scan_carry<<<dim3(24), dim3(256), 0, stream>>>(states, tmw, carr);
    k_mix_ln<<<dim3(4096), dim3(256), 0, stream>>>(y4, wkvl, carr, tmw, x, ln2w, ln2b, out, xx);

    // 5) k_cm = bf16(relu(xx2 @ Wck^T)^2)  (M=4096, N=3072, Ktot=768)
    k_gemm_bstat<1><<<dim3(256), dim3(512), 0, stream>>>(xx, wckb, (void*)kcm, 3072, 768, 1);

    // 6) out += k_cm @ Wcv^T  (M=4096, N=768, Ktot=3072), split-K=4, fp32 atomics
    k_gemm_bstat<3><<<dim3(256), dim3(512), 0, stream>>>(kcm, wcvb, (void*)out, 768, 3072, 4);
}

// Round 12
// 190.952 us; speedup vs baseline: 1.1929x; 1.1929x over previous
//
#include <hip/hip_runtime.h>
#include <hip/hip_bf16.h>

typedef __bf16 bf16_t;
typedef __bf16 bf16x8 __attribute__((ext_vector_type(8)));
typedef __bf16 bf16x4 __attribute__((ext_vector_type(4)));
typedef __bf16 bf16x2 __attribute__((ext_vector_type(2)));
typedef float  f32x4  __attribute__((ext_vector_type(4)));

#define LN_EPS 1e-5f

// B=8, T=512, C=768 -> M = 4096, 4C = 3072

// ---------------- async global->LDS helper (16B per lane, wave-uniform LDS base) ----
typedef __attribute__((address_space(1))) void gvoid_t;
typedef __attribute__((address_space(3))) void lvoid_t;
__device__ __forceinline__ void glds16(const void* g, void* l) {
    __builtin_amdgcn_global_load_lds((gvoid_t*)g, (lvoid_t*)l, 16, 0, 0);
}

// ---------------- fp32 -> bf16 conversion ----------------
__global__ __launch_bounds__(256) void k_cvt4(const float* __restrict__ s0,
                                              const float* __restrict__ s1,
                                              const float* __restrict__ s2,
                                              const float* __restrict__ s3,
                                              bf16_t* __restrict__ dst, int n4) {
    const float* s = (blockIdx.y == 0) ? s0 : (blockIdx.y == 1) ? s1 : (blockIdx.y == 2) ? s2 : s3;
    bf16_t* d = dst + (size_t)blockIdx.y * ((size_t)n4 * 4);
    int i = blockIdx.x * 256 + threadIdx.x;
    if (i < n4) {
        float4 v = ((const float4*)s)[i];
        bf16x4 o;
        o.x = (bf16_t)v.x; o.y = (bf16_t)v.y; o.z = (bf16_t)v.z; o.w = (bf16_t)v.w;
        ((bf16x4*)d)[i] = o;
    }
}

__global__ __launch_bounds__(256) void k_cvt2(const float* __restrict__ s0,
                                              const float* __restrict__ s1,
                                              bf16_t* __restrict__ dst, int n4) {
    const float* s = (blockIdx.y == 0) ? s0 : s1;
    bf16_t* d = dst + (size_t)blockIdx.y * ((size_t)n4 * 4);
    int i = blockIdx.x * 256 + threadIdx.x;
    if (i < n4) {
        float4 v = ((const float4*)s)[i];
        bf16x4 o;
        o.x = (bf16_t)v.x; o.y = (bf16_t)v.y; o.z = (bf16_t)v.z; o.w = (bf16_t)v.w;
        ((bf16x4*)d)[i] = o;
    }
}

// ---------------- LayerNorm (one block per row of C=768), bf16 out ----------------
__global__ __launch_bounds__(256) void k_ln(const float* __restrict__ x,
                                            const float* __restrict__ w,
                                            const float* __restrict__ b,
                                            bf16_t* __restrict__ out, int C) {
    int row = blockIdx.x;
    const float* xr = x + (long)row * C;
    int tid = threadIdx.x;
    float s = 0.f, s2 = 0.f;
    for (int i = tid; i < C; i += 256) { float v = xr[i]; s += v; s2 += v * v; }
    for (int m = 32; m; m >>= 1) { s += __shfl_xor(s, m, 64); s2 += __shfl_xor(s2, m, 64); }
    __shared__ float red[8];
    int wv = tid >> 6;
    if ((tid & 63) == 0) { red[wv] = s; red[4 + wv] = s2; }
    __syncthreads();
    float ts  = red[0] + red[1] + red[2] + red[3];
    float ts2 = red[4] + red[5] + red[6] + red[7];
    float mu  = ts / C;
    float var = ts2 / C - mu * mu;
    float rstd = rsqrtf(var + LN_EPS);
    bf16_t* orow = out + (long)row * C;
    for (int i = tid; i < C; i += 256)
        orow[i] = (bf16_t)((xr[i] - mu) * rstd * w[i] + b[i]);
}

// ------ bf16 MFMA GEMM: 8-phase-style interleave, 3-parity ring, counted vmcnt -----
// C[M][N](+=) A[M][Kslice] * Bw[N][Kslice]^T.  Tile 256x128, BK=64, 512 thr =
// 8 waves (4M x 2N), per-wave out 64x64 (acc 4x4), 12 K-tiles (Kloc=768).
// LDS: 3 parities x (A 256x64 + B 128x64) bf16 = 144 KB -> 2-TILE LOOKAHEAD:
// during tile t's phases we stage tile t+2; tile-top wait is s_waitcnt vmcnt(6)
// (tile t's 6 loads are the oldest; tile t+1's 6 STAY IN FLIGHT — never drains
// to 0 in the loop; in-order vmem retirement makes the count exact).
// Each tile = 4 phases: {8 ds_read_b128 (one C-quadrant x K=64) ; issue 1-2
// glds16 of t+2 ; lgkmcnt(0)+sched_barrier ; setprio(1) ; 8 MFMA ; setprio(0);
// s_barrier} — the m196/m218-verified fine interleave (T3+T4), with T5.
// Swizzle: byte-for-byte R8 math (measured 0 bank conflicts, refcheck'd):
// LDS[row][phys slot] = global[row][phys ^ (row&7)] via pre-swizzled global col;
// read slot = (kk*4+oct) ^ (fr&7).
// Grid 384 (48/XCD slab: 4bm x 12cix -> ~3.8MB L2 set).
// EPI 0: store bf16   EPI 1: store bf16(relu^2)   EPI 3: atomicAdd fp32
template <int EPI>
__global__ __launch_bounds__(512, 1) void k_gemm_p8(const bf16_t* __restrict__ A,
                                                    const bf16_t* __restrict__ Bw,
                                                    void* __restrict__ Cout,
                                                    int N, int Ktot, int nbn, int nks) {
    __shared__ __align__(16) bf16_t As[3][256][64];   // 96 KB
    __shared__ __align__(16) bf16_t Bs[3][128][64];   // 48 KB
    const int tid  = threadIdx.x;
    const int lane = tid & 63, wid = tid >> 6;        // wid 0..7
    const int wm = (wid >> 1) * 64, wn = (wid & 1) * 64;

    // XCD slab decode: grid == 384; per XCD 48 blocks = 4 bm x 12 cix (bijective)
    int bid = blockIdx.x;
    int xcd = bid & 7, loc = bid >> 3;                // loc 0..47
    int bm  = (xcd & 3) * 4 + loc / 12;               // 0..15
    int cix = (xcd >> 2) * 12 + loc % 12;             // 0..23
    int ks  = cix / nbn, bn = cix % nbn;

    const int fr  = lane & 15, oct = lane >> 4;       // frag row / k-octet
    const int f8  = fr & 7;
    const int ph0 = ((oct)     ^ f8) * 8;             // kk=0 16B-slot (elems)
    const int ph1 = ((oct + 4) ^ f8) * 8;             // kk=1

    f32x4 acc[4][4];
#pragma unroll
    for (int i = 0; i < 4; i++)
#pragma unroll
        for (int j = 0; j < 4; j++) acc[i][j] = (f32x4){0.f, 0.f, 0.f, 0.f};

    // staging: per tile, wave stages A rows [wid*32, +32) (4 glds16, 8 rows each)
    // and B rows [wid*16, +16) (2 glds16). lane -> row +(lane>>3), phys slot lane&7,
    // pre-swizzled global source slot (lane&7)^(lane>>3).   [R8-verified math]
    const int sr   = lane >> 3;                       // 0..7
    const int scol = ((lane & 7) ^ sr) * 8;
    const size_t ksoff = (size_t)ks * 768;
    const bf16_t* AgS = A  + (size_t)(bm * 256 + wid * 32 + sr) * Ktot + ksoff + scol;
    const bf16_t* BgS = Bw + (size_t)(bn * 128 + wid * 16 + sr) * Ktot + ksoff + scol;
    const size_t Kt8 = (size_t)8 * Ktot;

#define AGLDS(pr, tt, q) glds16(AgS + (size_t)(tt) * 64 + (q) * Kt8, &As[pr][wid * 32 + (q) * 8][0])
#define BGLDS(pr, tt, q) glds16(BgS + (size_t)(tt) * 64 + (q) * Kt8, &Bs[pr][wid * 16 + (q) * 8][0])

// one phase: quadrant P (mi-half = P>>1, ni-half = P&1), 8 ds_read + stage + 8 MFMA
#define PHASE(P, par, st, pr2, tt2)                                                          \
    do {                                                                                     \
        bf16x8 afr[2][2], bfr2[2][2];                                                        \
        _Pragma("unroll")                                                                    \
        for (int m2 = 0; m2 < 2; ++m2) {                                                     \
            afr[m2][0] = *(const bf16x8*)&As[par][wm + ((P >> 1) * 2 + m2) * 16 + fr][ph0];  \
            afr[m2][1] = *(const bf16x8*)&As[par][wm + ((P >> 1) * 2 + m2) * 16 + fr][ph1];  \
        }                                                                                    \
        _Pragma("unroll")                                                                    \
        for (int n2 = 0; n2 < 2; ++n2) {                                                     \
            bfr2[n2][0] = *(const bf16x8*)&Bs[par][wn + ((P & 1) * 2 + n2) * 16 + fr][ph0];  \
            bfr2[n2][1] = *(const bf16x8*)&Bs[par][wn + ((P & 1) * 2 + n2) * 16 + fr][ph1];  \
        }                                                                                    \
        if (st) {                                                                            \
            if ((P) == 0) { AGLDS(pr2, tt2, 0); AGLDS(pr2, tt2, 1); }                        \
            if ((P) == 1) { AGLDS(pr2, tt2, 2); AGLDS(pr2, tt2, 3); }                        \
            if ((P) == 2) { BGLDS(pr2, tt2, 0); }                                            \
            if ((P) == 3) { BGLDS(pr2, tt2, 1); }                                            \
        }                                                                                    \
        asm volatile("s_waitcnt lgkmcnt(0)" ::: "memory");                                   \
        __builtin_amdgcn_sched_barrier(0);                                                   \
        __builtin_amdgcn_s_setprio(1);                                                       \
        _Pragma("unroll")                                                                    \
        for (int kk = 0; kk < 2; ++kk)                                                       \
            _Pragma("unroll")                                                                \
            for (int m2 = 0; m2 < 2; ++m2)                                                   \
                _Pragma("unroll")                                                            \
                for (int n2 = 0; n2 < 2; ++n2)                                               \
                    acc[(P >> 1) * 2 + m2][(P & 1) * 2 + n2] =                               \
                        __builtin_amdgcn_mfma_f32_16x16x32_bf16(                             \
                            afr[m2][kk], bfr2[n2][kk],                                       \
                            acc[(P >> 1) * 2 + m2][(P & 1) * 2 + n2], 0, 0, 0);              \
        __builtin_amdgcn_s_setprio(0);                                                       \
        __builtin_amdgcn_s_barrier();                                                        \
        __builtin_amdgcn_sched_barrier(0);                                                   \
    } while (0)

    // prologue: stage tiles 0 (parity 0) and 1 (parity 1): 6 glds each per wave
    AGLDS(0, 0, 0); AGLDS(0, 0, 1); AGLDS(0, 0, 2); AGLDS(0, 0, 3);
    BGLDS(0, 0, 0); BGLDS(0, 0, 1);
    AGLDS(1, 1, 0); AGLDS(1, 1, 1); AGLDS(1, 1, 2); AGLDS(1, 1, 3);
    BGLDS(1, 1, 0); BGLDS(1, 1, 1);

    int par = 0, pr2 = 2;
    for (int t = 0; t < 12; ++t) {
        if (t < 11) { asm volatile("s_waitcnt vmcnt(6)" ::: "memory"); }   // tile t landed,
        else        { asm volatile("s_waitcnt vmcnt(0)" ::: "memory"); }   // t+1 in flight
        __builtin_amdgcn_s_barrier();                 // collective: tile t resident
        __builtin_amdgcn_sched_barrier(0);
        const bool st  = (t < 10);
        const int  tt2 = t + 2;
        PHASE(0, par, st, pr2, tt2);
        PHASE(1, par, st, pr2, tt2);
        PHASE(2, par, st, pr2, tt2);
        PHASE(3, par, st, pr2, tt2);
        par = (par == 2) ? 0 : par + 1;
        pr2 = (pr2 == 2) ? 0 : pr2 + 1;
    }

#undef PHASE
#undef AGLDS
#undef BGLDS

    const int row0 = bm * 256 + wm, col0 = bn * 128 + wn;
#pragma unroll
    for (int mi = 0; mi < 4; mi++) {
#pragma unroll
        for (int ni = 0; ni < 4; ni++) {
            int row = row0 + mi * 16 + oct * 4;       // C/D: col=lane&15, row=(lane>>4)*4+r
            int col = col0 + ni * 16 + fr;
#pragma unroll
            for (int r = 0; r < 4; r++) {
                float val = acc[mi][ni][r];
                size_t off = (size_t)(row + r) * N + col;
                if (EPI == 0) {
                    ((bf16_t*)Cout)[off] = (bf16_t)val;
                } else if (EPI == 1) {
                    float t = fmaxf(val, 0.f);
                    ((bf16_t*)Cout)[off] = (bf16_t)(t * t);
                } else {
                    atomicAdd(&((float*)Cout)[off], val);
                }
            }
        }
    }
}

// ---------------- WKV chunked scan (y4 bf16), 2 channels/thread ----------------
// y4 layout per (b,t): [ r(768) | k(768) | v(768) | router(768) ]
__global__ __launch_bounds__(256) void k_scan_local(const bf16_t* __restrict__ y4,
                                                    const float* __restrict__ tmw,
                                                    float* __restrict__ wkvl,
                                                    float* __restrict__ states) {
    int idx = blockIdx.x * 256 + threadIdx.x;  // 8*16*384 = 49152
    int cp  = idx % 384;
    int rem = idx / 384;
    int ch  = rem & 15;
    int b   = rem >> 4;
    int c   = cp * 2;
    float d0 = expf(-expf(tmw[c]));
    float d1 = expf(-expf(tmw[c + 1]));
    const bf16_t* base = y4 + ((size_t)(b * 512 + ch * 32)) * 3072 + c;
    float*        wout = wkvl + ((size_t)(b * 512 + ch * 32)) * 768 + c;
    float s0 = 0.f, s1 = 0.f;
#pragma unroll 4
    for (int i = 0; i < 32; i++) {
        bf16x2 k2 = *(const bf16x2*)(base + (size_t)i * 3072 + 768);
        bf16x2 v2 = *(const bf16x2*)(base + (size_t)i * 3072 + 1536);
        s0 = s0 * d0 + (float)k2.x * (float)v2.x;
        s1 = s1 * d1 + (float)k2.y * (float)v2.y;
        *(float2*)(wout + (size_t)i * 768) = make_float2(s0, s1);
    }
    *(float2*)(states + ((size_t)(b * 16 + ch)) * 768 + c) = make_float2(s0, s1);
}

__global__ __launch_bounds__(256) void k_scan_carry(const float* __restrict__ states,
                                                    const float* __restrict__ tmw,
                                                    float* __restrict__ carries) {
    int idx = blockIdx.x * 256 + threadIdx.x;  // b*768 + c
    int c = idx % 768, b = idx / 768;
    float dL = expf(-expf(tmw[c]) * 32.f);
    float s = 0.f;
    for (int ch = 0; ch < 16; ch++) {
        size_t o = ((size_t)(b * 16 + ch)) * 768 + c;
        carries[o] = s;
        s = s * dL + states[o];
    }
}

// ---------------- mix + LN2 fused: one block per (b,t) row ----------------
// out = x + r*((wkv_local + carry*d^(tmod+1)) * sigmoid(router));  xx2 = LN2(out) bf16
// (out is d_out; the final GEMM atomically adds the channel-mix on top)
__global__ __launch_bounds__(256) void k_mix_ln(const bf16_t* __restrict__ y4,
                                                const float* __restrict__ wkvl,
                                                const float* __restrict__ carries,
                                                const float* __restrict__ tmw,
                                                const float* __restrict__ x,
                                                const float* __restrict__ w2,
                                                const float* __restrict__ b2,
                                                float* __restrict__ out,
                                                bf16_t* __restrict__ xx2) {
    int bt = blockIdx.x;
    int t = bt & 511, b = bt >> 9;
    int tid = threadIdx.x;
    const bf16_t* yrow = y4 + (size_t)bt * 3072;
    const float*  wl   = wkvl + (size_t)bt * 768;
    const float*  cr   = carries + ((size_t)(b * 16) + (t >> 5)) * 768;
    const float*  xr   = x + (size_t)bt * 768;
    float tn = (float)((t & 31) + 1);

    float vals[3];
    float s = 0.f, s2 = 0.f;
#pragma unroll
    for (int j = 0; j < 3; j++) {
        int c = tid + j * 256;
        float rr = (float)yrow[c];
        float gg = (float)yrow[c + 2304];
        float wk = wl[c] + cr[c] * expf(-expf(tmw[c]) * tn);
        float sig = 1.f / (1.f + expf(-gg));
        float o = fmaf(rr, wk * sig, xr[c]);
        vals[j] = o; s += o; s2 += o * o;
    }
    for (int m = 32; m; m >>= 1) { s += __shfl_xor(s, m, 64); s2 += __shfl_xor(s2, m, 64); }
    __shared__ float red[8];
    int wv = tid >> 6;
    if ((tid & 63) == 0) { red[wv] = s; red[4 + wv] = s2; }
    __syncthreads();
    float ts  = red[0] + red[1] + red[2] + red[3];
    float ts2 = red[4] + red[5] + red[6] + red[7];
    float mu  = ts * (1.f / 768.f);
    float var = ts2 * (1.f / 768.f) - mu * mu;
    float rstd = rsqrtf(var + LN_EPS);
    float* orow = out + (size_t)bt * 768;
    bf16_t* xo = xx2 + (size_t)bt * 768;
#pragma unroll
    for (int j = 0; j < 3; j++) {
        int c = tid + j * 256;
        orow[c] = vals[j];
        xo[c] = (bf16_t)((vals[j] - mu) * rstd * w2[c] + b2[c]);
    }
}

// ---------------- host-side launch ----------------
extern "C" void kernel_launch(void* const* d_in, const int* in_sizes, int n_in,
                              void* d_out, int out_size, void* d_ws, size_t ws_size,
                              hipStream_t stream) {
    const float* x    = (const float*)d_in[0];
    const float* ln1w = (const float*)d_in[1];
    const float* ln1b = (const float*)d_in[2];
    const float* Wr   = (const float*)d_in[3];
    const float* Wk   = (const float*)d_in[4];
    const float* Wv   = (const float*)d_in[5];
    const float* tmw  = (const float*)d_in[6];
    const float* Wrt  = (const float*)d_in[7];
    const float* ln2w = (const float*)d_in[8];
    const float* ln2b = (const float*)d_in[9];
    const float* Wck  = (const float*)d_in[10];
    const float* Wcv  = (const float*)d_in[11];
    float* out = (float*)d_out;
    char* ws = (char*)d_ws;

    // workspace layout (bytes)
    bf16_t* xx     = (bf16_t*)(ws + 0);          // 4096*768 bf16 (xx, reused as xx2)
    bf16_t* wcat   = (bf16_t*)(ws + 6291456);    // [4][768][768] bf16 (r,k,v,router)
    bf16_t* wckb   = (bf16_t*)(ws + 11010048);   // [3072][768] bf16
    bf16_t* wcvb   = (bf16_t*)(ws + 15728640);   // [768][3072] bf16
    bf16_t* y4     = (bf16_t*)(ws + 20447232);   // [4096][3072] bf16
    bf16_t* kcm    = (bf16_t*)(ws + 20447232);   // reuses y4 after mix
    float*  wkvl   = (float*)(ws + 70778880);    // [4096][768] fp32
    float*  states = (float*)(ws + 83361792);    // [8][16][768]
    float*  carr   = (float*)(ws + 83755008);    // [8][16][768]

    // 1) weights -> bf16
    const int n768 = 768 * 768 / 4;
    const int nbig = 3072 * 768 / 4;
    k_cvt4<<<dim3(576, 4), dim3(256), 0, stream>>>(Wr, Wk, Wv, Wrt, wcat, n768);
    k_cvt2<<<dim3(2304, 2), dim3(256), 0, stream>>>(Wck, Wcv, wckb, nbig);

    // 2) LN1
    k_ln<<<dim3(4096), dim3(256), 0, stream>>>(x, ln1w, ln1b, xx, 768);

    // 3) fused r|k|v|router GEMM: y4 = xx @ wcat^T  (M=4096, N=3072, Ktot=768)
    k_gemm_p8<0><<<dim3(384), dim3(512), 0, stream>>>(xx, wcat, (void*)y4, 3072, 768, 24, 1);

    // 4) wkv scan + mix(+LN2): writes x1 -> d_out, xx2 -> xx
    k_scan_local<<<dim3(192), dim3(256), 0, stream>>>(y4, tmw, wkvl, states);
    k_scan_carry<<<dim3(24), dim3(256), 0, stream>>>(states, tmw, carr);
    k_mix_ln<<<dim3(4096), dim3(256), 0, stream>>>(y4, wkvl, carr, tmw, x, ln2w, ln2b, out, xx);

    // 5) k_cm = bf16(relu(xx2 @ Wck^T)^2)  (M=4096, N=3072, Ktot=768)
    k_gemm_p8<1><<<dim3(384), dim3(512), 0, stream>>>(xx, wckb, (void*)kcm, 3072, 768, 24, 1);

    // 6) out += k_cm @ Wcv^T  (M=4096, N=768, Ktot=3072), split-K=4, fp32 atomics
    k_gemm_p8<3><<<dim3(384), dim3(512), 0, stream>>>(kcm, wcvb, (void*)out, 768, 3072, 6, 4);
}